// Round 3
// baseline (496.333 us; speedup 1.0000x reference)
//
#include <hip/hip_runtime.h>
#include <hip/hip_bf16.h>
#include <cstdint>
#include <cstddef>

typedef __bf16 bf16_t;
typedef bf16_t bf16x8 __attribute__((ext_vector_type(8)));
typedef float  f32x4  __attribute__((ext_vector_type(4)));

#define FWHT_N 4096

// ---- GEMM geometry: 256x256 tile, K-step 32, 4-deep LDS pipeline ----
#define BM 256
#define BN 256
#define KSTEP 32
#define ABYTES 16384          // 256 rows x 32 k x 2B (one step's A)
#define BUFBYTES 32768        // A + B per step-buffer
#define NBUF 4                // 4 x 32 KiB = 128 KiB LDS

// ---------------------------------------------------------------------------
// 16-point in-register FWHT (4 radix-2 stages, unnormalized)
// ---------------------------------------------------------------------------
__device__ __forceinline__ void fwht16(float v[16]) {
#pragma unroll
    for (int h = 1; h < 16; h <<= 1) {
#pragma unroll
        for (int i = 0; i < 16; ++i) {
            if (!(i & h)) {
                const float a = v[i];
                const float b = v[i | h];
                v[i]     = a + b;
                v[i | h] = a - b;
            }
        }
    }
}

// padded LDS address: +1 word every 32 => all round patterns are 2-way (free)
__device__ __forceinline__ int pad(int i) { return i + (i >> 5); }

// ---------------------------------------------------------------------------
// Kernel 1: normalized FWHT along rows of W, emit bf16 W'
// W' = H * W[o,:] / 64  (H symmetric => x@W'^T == fwht(x)@W^T)
// ---------------------------------------------------------------------------
__global__ __launch_bounds__(256) void fwht_rows_bf16(const float* __restrict__ W,
                                                      bf16_t* __restrict__ Wt) {
    __shared__ float lds[FWHT_N + (FWHT_N >> 5)];
    const int r = blockIdx.x;
    const int t = threadIdx.x;

    float v[16];

    // ---- round 0: bits 0-3, i = 16t + k (contiguous) ----
    const float4* src = (const float4*)(W + (size_t)r * FWHT_N + 16 * t);
    {
        const float4 a0 = src[0], a1 = src[1], a2 = src[2], a3 = src[3];
        v[0] = a0.x; v[1] = a0.y; v[2]  = a0.z; v[3]  = a0.w;
        v[4] = a1.x; v[5] = a1.y; v[6]  = a1.z; v[7]  = a1.w;
        v[8] = a2.x; v[9] = a2.y; v[10] = a2.z; v[11] = a2.w;
        v[12] = a3.x; v[13] = a3.y; v[14] = a3.z; v[15] = a3.w;
    }
    fwht16(v);
    {
        const int base = 16 * t + (t >> 1);
#pragma unroll
        for (int k = 0; k < 16; ++k) lds[base + k] = v[k];
    }
    __syncthreads();

    // ---- round 1: bits 4-7 ----
    const int b1 = ((t >> 4) << 8) | (t & 15);
#pragma unroll
    for (int k = 0; k < 16; ++k) v[k] = lds[pad(b1 + (k << 4))];
    fwht16(v);
#pragma unroll
    for (int k = 0; k < 16; ++k) lds[pad(b1 + (k << 4))] = v[k];
    __syncthreads();

    // ---- round 2: bits 8-11 ----
#pragma unroll
    for (int k = 0; k < 16; ++k) v[k] = lds[pad(t + (k << 8))];
    fwht16(v);

    const float s = 0.015625f;  // 1/sqrt(4096)
    bf16_t* dst = Wt + (size_t)r * FWHT_N + t;
#pragma unroll
    for (int k = 0; k < 16; ++k) dst[k << 8] = (bf16_t)(v[k] * s);
}

// ---------------------------------------------------------------------------
// Kernel 2: x fp32 -> bf16, 16B/lane stores
// ---------------------------------------------------------------------------
__global__ __launch_bounds__(256) void cvt_f32_bf16(const float4* __restrict__ x,
                                                    bf16x8* __restrict__ y) {
    const size_t i = (size_t)blockIdx.x * 256 + threadIdx.x;
    const float4 a = x[2 * i];
    const float4 b = x[2 * i + 1];
    bf16x8 o;
    o[0] = (bf16_t)a.x; o[1] = (bf16_t)a.y; o[2] = (bf16_t)a.z; o[3] = (bf16_t)a.w;
    o[4] = (bf16_t)b.x; o[5] = (bf16_t)b.y; o[6] = (bf16_t)b.z; o[7] = (bf16_t)b.w;
    y[i] = o;
}

// ---------------------------------------------------------------------------
// Kernel 3: C[M,N] = A[M,K] * B[N,K]^T + bias   (bf16 in, fp32 out)
// 256x256 tile, 8 waves (2Mx4N), KSTEP=32, NBUF=4 rotating LDS pipeline.
// Round-3: m201-style phase schedule. Iteration = 2 K-steps, 4 phases:
//   phase (kstep e/o, M-half mh): { 4-8 ds_read_b128 ; 2 global_load_lds ;
//     s_barrier ; lgkmcnt(0) ; setprio(1) ; 16 MFMA ; setprio(0) ; s_barrier }
//   B-frags read once per kstep (reused across the two M-half phases).
//   vmcnt(8) attached to the trailing barriers of phases 1 and 3 only:
//     invariant at iter-s start: steps 2s,2s+1 landed; {2s+1? no:} outstanding
//     = {2s+1 retired, 2s+2, 2s+3-} ... uniform: mid-iter vmcnt(8) retires
//     step 2s+1 (needed by phase 2), end-iter vmcnt(8) retires step 2s+2
//     (needed by next iter phase 0). Stage targets never collide with live
//     buffers (stage 2s+3: distinct buf; stage 2s+4: its buf's last reader
//     was phase 1, two barriers earlier).
// ---------------------------------------------------------------------------
__device__ __forceinline__ void g2lds16(const bf16_t* g, bf16_t* l) {
    __builtin_amdgcn_global_load_lds((__attribute__((address_space(1))) void*)g,
                                     (__attribute__((address_space(3))) void*)l,
                                     16, 0, 0);
}

__global__ __launch_bounds__(512, 2) void gemm256_bt_bias(
    const bf16_t* __restrict__ A,
    const bf16_t* __restrict__ Bm,
    const float* __restrict__ bias,
    float* __restrict__ C,
    int M, int N, int K)
{
    __shared__ __align__(16) char lds[NBUF * BUFBYTES];  // 128 KiB

    const int tid  = threadIdx.x;
    const int wave = tid >> 6;
    const int lane = tid & 63;
    const int quad = lane >> 4;
    const int l16  = lane & 15;

    // ---- bijective XCD-chunked swizzle (nwg = 512, % 8 == 0) ----
    const int nbx  = N / BN;                                  // 16
    const int flat = blockIdx.y * nbx + blockIdx.x;
    const int per  = (nbx * (M / BM)) >> 3;                   // 64
    const int nf   = (flat & 7) * per + (flat >> 3);
    const int m0   = (nf / nbx) * BM;
    const int n0   = (nf % nbx) * BN;

    const int wm = (wave >> 2) * 128;   // 2 M-warps
    const int wn = (wave & 3) * 64;     // 4 N-warps

    // ---- staging map: linear LDS dest <- inverse-swizzled global source ----
    const int srow = wave * 16 + (lane >> 2);                      // 0..127
    const int scb  = (((lane & 3) ^ ((lane >> 3) & 3)) << 4);      // bytes in 64B k-run
    const int L0   = wave * 1024 + lane * 16;                      // linear LDS bytes

    const bf16_t* gA0 = A  + (size_t)(m0 + srow)       * K + (scb >> 1);
    const bf16_t* gA1 = A  + (size_t)(m0 + srow + 128) * K + (scb >> 1);
    const bf16_t* gB0 = Bm + (size_t)(n0 + srow)       * K + (scb >> 1);
    const bf16_t* gB1 = Bm + (size_t)(n0 + srow + 128) * K + (scb >> 1);

    // ---- ds_read fragment addresses (same swizzle on the read side) ----
    const int cbr   = ((quad ^ ((lane >> 1) & 3)) << 4);
    const int aoff  = l16 * 64 + cbr;
    const int abase = ((wm >> 4) << 10) + aoff;            // + mi*1024
    const int bbase = ABYTES + ((wn >> 4) << 10) + aoff;   // + ni*1024

    f32x4 acc[8][4] = {};
    bf16x8 aF[4], aG[4], bE[4], bO[4];

    const int NT = K / KSTEP;   // 128
    const int NIT = NT / 2;     // 64

    auto stageHalf = [&](int s, int h) {   // h=0: A halves, h=1: B halves
        char* d = &lds[(s & (NBUF - 1)) * BUFBYTES];
        const int ko = (s < NT ? s : NT - 1) * KSTEP;   // clamped tail keeps vmcnt uniform
        if (h == 0) {
            g2lds16(gA0 + ko, (bf16_t*)(d + L0));
            g2lds16(gA1 + ko, (bf16_t*)(d + L0 + 8192));
        } else {
            g2lds16(gB0 + ko, (bf16_t*)(d + ABYTES + L0));
            g2lds16(gB1 + ko, (bf16_t*)(d + ABYTES + L0 + 8192));
        }
    };
    auto dsA = [&](const char* buf, int mh, bf16x8 (&fa)[4]) {
#pragma unroll
        for (int i = 0; i < 4; ++i)
            fa[i] = *(const bf16x8*)(buf + abase + ((mh * 4 + i) << 10));
    };
    auto dsB = [&](const char* buf, bf16x8 (&fb)[4]) {
#pragma unroll
        for (int ni = 0; ni < 4; ++ni)
            fb[ni] = *(const bf16x8*)(buf + bbase + (ni << 10));
    };
    auto mf16 = [&](int mh, bf16x8 (&fa)[4], bf16x8 (&fb)[4]) {
        __builtin_amdgcn_s_setprio(1);
#pragma unroll
        for (int mi = 0; mi < 4; ++mi)
#pragma unroll
            for (int ni = 0; ni < 4; ++ni)
                acc[mh * 4 + mi][ni] = __builtin_amdgcn_mfma_f32_16x16x32_bf16(
                    fa[mi], fb[ni], acc[mh * 4 + mi][ni], 0, 0, 0);
        __builtin_amdgcn_s_setprio(0);
    };

#define PHASE_BAR()  do { __builtin_amdgcn_s_barrier(); \
                          asm volatile("s_waitcnt lgkmcnt(0)" ::: "memory"); \
                          __builtin_amdgcn_sched_barrier(0); } while (0)
#define TAIL_BAR()   do { __builtin_amdgcn_s_barrier(); \
                          __builtin_amdgcn_sched_barrier(0); } while (0)
#define TAIL_BARV()  do { asm volatile("s_waitcnt vmcnt(8)" ::: "memory"); \
                          __builtin_amdgcn_s_barrier(); \
                          __builtin_amdgcn_sched_barrier(0); } while (0)

    // ---- prologue: stage steps 0,1,2 (12 in flight); retire step 0 ----
    stageHalf(0, 0); stageHalf(0, 1);
    stageHalf(1, 0); stageHalf(1, 1);
    stageHalf(2, 0); stageHalf(2, 1);
    TAIL_BARV();   // vmcnt(8): step 0 landed; {1,2} outstanding (= steady invariant)

#pragma unroll 1
    for (int s = 0; s < NIT; ++s) {
        const int e = 2 * s;
        const char* bufE = &lds[(e & (NBUF - 1)) * BUFBYTES];
        const char* bufO = &lds[((e + 1) & (NBUF - 1)) * BUFBYTES];

        // phase 0: kstep e, M-half 0
        dsB(bufE, bE);
        dsA(bufE, 0, aF);
        stageHalf(e + 3, 0);
        PHASE_BAR();
        mf16(0, aF, bE);
        TAIL_BAR();

        // phase 1: kstep e, M-half 1
        dsA(bufE, 1, aG);
        stageHalf(e + 3, 1);
        PHASE_BAR();
        mf16(1, aG, bE);
        TAIL_BARV();   // retires step e+1 (needed by phase 2)

        // phase 2: kstep e+1, M-half 0
        dsB(bufO, bO);
        dsA(bufO, 0, aF);
        stageHalf(e + 4, 0);
        PHASE_BAR();
        mf16(0, aF, bO);
        TAIL_BAR();

        // phase 3: kstep e+1, M-half 1
        dsA(bufO, 1, aG);
        stageHalf(e + 4, 1);
        PHASE_BAR();
        mf16(1, aG, bO);
        TAIL_BARV();   // retires step e+2 (needed by next iter phase 0)
    }
    asm volatile("s_waitcnt vmcnt(0)" ::: "memory");   // drain clamped tail stages

#undef PHASE_BAR
#undef TAIL_BAR
#undef TAIL_BARV

    // ---- epilogue: C = acc + bias (C/D map: col=lane&15, row=quad*4+r) ----
    const int crow = quad * 4;
#pragma unroll
    for (int ni = 0; ni < 4; ++ni) {
        const int n  = n0 + wn + ni * 16 + l16;
        const float bv = bias[n];
#pragma unroll
        for (int mi = 0; mi < 8; ++mi) {
            const int mb = m0 + wm + mi * 16 + crow;
#pragma unroll
            for (int r = 0; r < 4; ++r)
                C[(size_t)(mb + r) * N + n] = acc[mi][ni][r] + bv;
        }
    }
}

// ---------------------------------------------------------------------------
extern "C" void kernel_launch(void* const* d_in, const int* in_sizes, int n_in,
                              void* d_out, int out_size, void* d_ws, size_t ws_size,
                              hipStream_t stream) {
    const float* x = (const float*)d_in[0];   // [B,S,K] fp32
    const float* W = (const float*)d_in[1];   // [N,K]   fp32
    const float* b = (const float*)d_in[2];   // [N]     fp32
    float* out = (float*)d_out;               // [B,S,N] fp32

    const int K = 4096;
    const int N = 4096;
    const int M = in_sizes[0] / K;            // 8192

    bf16_t* xb = (bf16_t*)d_ws;               // M*K bf16 = 64 MiB
    bf16_t* Wt = xb + (size_t)M * K;          // N*K bf16 = 32 MiB

    hipLaunchKernelGGL(fwht_rows_bf16, dim3(N), dim3(256), 0, stream, W, Wt);

    const int cvt_blocks = (int)(((size_t)M * K) / 8 / 256);  // 16384
    hipLaunchKernelGGL(cvt_f32_bf16, dim3(cvt_blocks), dim3(256), 0, stream,
                       (const float4*)x, (bf16x8*)xb);

    hipLaunchKernelGGL(gemm256_bt_bias, dim3(N / BN, M / BM), dim3(512), 0, stream,
                       xb, Wt, b, out, M, N, K);
}

// Round 5
// 491.415 us; speedup vs baseline: 1.0100x; 1.0100x over previous
//
#include <hip/hip_runtime.h>
#include <hip/hip_bf16.h>
#include <cstdint>
#include <cstddef>

typedef __bf16 bf16_t;
typedef bf16_t bf16x8 __attribute__((ext_vector_type(8)));
typedef float  f32x4  __attribute__((ext_vector_type(4)));

#define FWHT_N 4096

// ---- GEMM geometry: 256x256 tile, K-step 32, 5-deep LDS pipeline ----
#define BM 256
#define BN 256
#define KSTEP 32
#define ABYTES 16384          // 256 rows x 32 k x 2B (one step's A)
#define BUFBYTES 32768        // A + B per step-buffer
#define NBUF 5                // 5 x 32 KiB = 160 KiB LDS (full CU pool)

// ---------------------------------------------------------------------------
// 16-point in-register FWHT (4 radix-2 stages, unnormalized)
// ---------------------------------------------------------------------------
__device__ __forceinline__ void fwht16(float v[16]) {
#pragma unroll
    for (int h = 1; h < 16; h <<= 1) {
#pragma unroll
        for (int i = 0; i < 16; ++i) {
            if (!(i & h)) {
                const float a = v[i];
                const float b = v[i | h];
                v[i]     = a + b;
                v[i | h] = a - b;
            }
        }
    }
}

// padded LDS address: +1 word every 32 => all round patterns are 2-way (free)
__device__ __forceinline__ int pad(int i) { return i + (i >> 5); }

// ---------------------------------------------------------------------------
// Kernel 1: normalized FWHT along rows of W, emit bf16 W'
// W' = H * W[o,:] / 64  (H symmetric => x@W'^T == fwht(x)@W^T)
// ---------------------------------------------------------------------------
__global__ __launch_bounds__(256) void fwht_rows_bf16(const float* __restrict__ W,
                                                      bf16_t* __restrict__ Wt) {
    __shared__ float lds[FWHT_N + (FWHT_N >> 5)];
    const int r = blockIdx.x;
    const int t = threadIdx.x;

    float v[16];

    // ---- round 0: bits 0-3, i = 16t + k (contiguous) ----
    const float4* src = (const float4*)(W + (size_t)r * FWHT_N + 16 * t);
    {
        const float4 a0 = src[0], a1 = src[1], a2 = src[2], a3 = src[3];
        v[0] = a0.x; v[1] = a0.y; v[2]  = a0.z; v[3]  = a0.w;
        v[4] = a1.x; v[5] = a1.y; v[6]  = a1.z; v[7]  = a1.w;
        v[8] = a2.x; v[9] = a2.y; v[10] = a2.z; v[11] = a2.w;
        v[12] = a3.x; v[13] = a3.y; v[14] = a3.z; v[15] = a3.w;
    }
    fwht16(v);
    {
        const int base = 16 * t + (t >> 1);
#pragma unroll
        for (int k = 0; k < 16; ++k) lds[base + k] = v[k];
    }
    __syncthreads();

    // ---- round 1: bits 4-7 ----
    const int b1 = ((t >> 4) << 8) | (t & 15);
#pragma unroll
    for (int k = 0; k < 16; ++k) v[k] = lds[pad(b1 + (k << 4))];
    fwht16(v);
#pragma unroll
    for (int k = 0; k < 16; ++k) lds[pad(b1 + (k << 4))] = v[k];
    __syncthreads();

    // ---- round 2: bits 8-11 ----
#pragma unroll
    for (int k = 0; k < 16; ++k) v[k] = lds[pad(t + (k << 8))];
    fwht16(v);

    const float s = 0.015625f;  // 1/sqrt(4096)
    bf16_t* dst = Wt + (size_t)r * FWHT_N + t;
#pragma unroll
    for (int k = 0; k < 16; ++k) dst[k << 8] = (bf16_t)(v[k] * s);
}

// ---------------------------------------------------------------------------
// Kernel 2: x fp32 -> bf16, 16B/lane stores
// ---------------------------------------------------------------------------
__global__ __launch_bounds__(256) void cvt_f32_bf16(const float4* __restrict__ x,
                                                    bf16x8* __restrict__ y) {
    const size_t i = (size_t)blockIdx.x * 256 + threadIdx.x;
    const float4 a = x[2 * i];
    const float4 b = x[2 * i + 1];
    bf16x8 o;
    o[0] = (bf16_t)a.x; o[1] = (bf16_t)a.y; o[2] = (bf16_t)a.z; o[3] = (bf16_t)a.w;
    o[4] = (bf16_t)b.x; o[5] = (bf16_t)b.y; o[6] = (bf16_t)b.z; o[7] = (bf16_t)b.w;
    y[i] = o;
}

// ---------------------------------------------------------------------------
// Kernel 3: C[M,N] = A[M,K] * B[N,K]^T + bias   (bf16 in, fp32 out)
// 256x256 tile, 8 waves (2Mx4N), KSTEP=32, NBUF=5 rotating LDS pipeline.
// Round-4/5: round-2 schedule with barrier count HALVED (1 barrier / 2 K-steps).
// Window w (steps e=2w, e+1); entry invariant: steps e,e+1 landed+visible,
// outstanding gloads = {e+2} (4), setB = frags(e-1) in regs.
//   stage(e+3)->buf(e+3)%5 ; stage(e+4)->buf(e+4)%5==(e-1)%5  [readers done
//     in window w-1, cross-barrier]
//   loadFrags(e)->setA ; MFMA(setB=e-1) ; loadFrags(e+1)->setB ; MFMA(setA=e)
//   lgkmcnt(0)   [all my ds_reads retired => buffer recycle provably safe]
//   vmcnt(4)     [retires e+2,e+3 (needed next window); e+4 stays in flight]
//   s_barrier ; sched_barrier(0)
// MFMA(127) peels off after the loop (setB).
// ---------------------------------------------------------------------------
__device__ __forceinline__ void g2lds16(const bf16_t* g, bf16_t* l) {
    __builtin_amdgcn_global_load_lds((__attribute__((address_space(1))) void*)g,
                                     (__attribute__((address_space(3))) void*)l,
                                     16, 0, 0);
}

__global__ __launch_bounds__(512, 2) void gemm256_bt_bias(
    const bf16_t* __restrict__ A,
    const bf16_t* __restrict__ Bm,
    const float* __restrict__ bias,
    float* __restrict__ C,
    int M, int N, int K)
{
    __shared__ __align__(16) char lds[NBUF * BUFBYTES];  // 160 KiB

    const int tid  = threadIdx.x;
    const int wave = tid >> 6;
    const int lane = tid & 63;
    const int quad = lane >> 4;
    const int l16  = lane & 15;

    // ---- bijective XCD-chunked swizzle (nwg = 512, % 8 == 0) ----
    const int nbx  = N / BN;                                  // 16
    const int flat = blockIdx.y * nbx + blockIdx.x;
    const int per  = (nbx * (M / BM)) >> 3;                   // 64
    const int nf   = (flat & 7) * per + (flat >> 3);
    const int m0   = (nf / nbx) * BM;
    const int n0   = (nf % nbx) * BN;

    const int wm = (wave >> 2) * 128;   // 2 M-warps
    const int wn = (wave & 3) * 64;     // 4 N-warps

    // ---- staging map: linear LDS dest <- inverse-swizzled global source ----
    const int srow = wave * 16 + (lane >> 2);                      // 0..127
    const int scb  = (((lane & 3) ^ ((lane >> 3) & 3)) << 4);      // bytes in 64B k-run
    const int L0   = wave * 1024 + lane * 16;                      // linear LDS bytes

    const bf16_t* gA0 = A  + (size_t)(m0 + srow)       * K + (scb >> 1);
    const bf16_t* gA1 = A  + (size_t)(m0 + srow + 128) * K + (scb >> 1);
    const bf16_t* gB0 = Bm + (size_t)(n0 + srow)       * K + (scb >> 1);
    const bf16_t* gB1 = Bm + (size_t)(n0 + srow + 128) * K + (scb >> 1);

    // ---- ds_read fragment addresses (same swizzle on the read side) ----
    const int cbr   = ((quad ^ ((lane >> 1) & 3)) << 4);
    const int aoff  = l16 * 64 + cbr;
    const int abase = ((wm >> 4) << 10) + aoff;            // + mi*1024
    const int bbase = ABYTES + ((wn >> 4) << 10) + aoff;   // + ni*1024

    f32x4 acc[8][4] = {};
    bf16x8 aA[8], bA[4], aB[8], bB[4];

    const int NT = K / KSTEP;   // 128
    const int NW = NT / 2;      // 64

    auto stageStep = [&](int s, int idx) {
        char* d = &lds[idx * BUFBYTES];
        const int ko = (s < NT ? s : NT - 1) * KSTEP;   // clamped tail keeps vmcnt uniform
        g2lds16(gA0 + ko, (bf16_t*)(d + L0));
        g2lds16(gA1 + ko, (bf16_t*)(d + L0 + 8192));
        g2lds16(gB0 + ko, (bf16_t*)(d + ABYTES + L0));
        g2lds16(gB1 + ko, (bf16_t*)(d + ABYTES + L0 + 8192));
    };
    auto loadFrags = [&](int idx, bf16x8 (&fa)[8], bf16x8 (&fb)[4]) {
        const char* buf = &lds[idx * BUFBYTES];
#pragma unroll
        for (int ni = 0; ni < 4; ++ni)
            fb[ni] = *(const bf16x8*)(buf + bbase + (ni << 10));
#pragma unroll
        for (int mi = 0; mi < 8; ++mi)
            fa[mi] = *(const bf16x8*)(buf + abase + (mi << 10));
    };
    auto mfmaAll = [&](bf16x8 (&fa)[8], bf16x8 (&fb)[4]) {
        __builtin_amdgcn_s_setprio(1);
#pragma unroll
        for (int mi = 0; mi < 8; ++mi)
#pragma unroll
            for (int ni = 0; ni < 4; ++ni)
                acc[mi][ni] = __builtin_amdgcn_mfma_f32_16x16x32_bf16(
                    fa[mi], fb[ni], acc[mi][ni], 0, 0, 0);
        __builtin_amdgcn_s_setprio(0);
    };

    // ---- prologue: stage 0,1,2 (12 loads); retire steps 0,1; {2} in flight ----
    stageStep(0, 0);
    stageStep(1, 1);
    stageStep(2, 2);
    asm volatile("s_waitcnt vmcnt(4)" ::: "memory");
    __builtin_amdgcn_s_barrier();
    __builtin_amdgcn_sched_barrier(0);

    int ib = 0;
#pragma unroll 1
    for (int w = 0; w < NW; ++w) {
        const int e  = 2 * w;
        const int i0 = ib;
        const int i1 = (i0 + 1 >= NBUF) ? i0 + 1 - NBUF : i0 + 1;
        const int i3 = (i0 + 3 >= NBUF) ? i0 + 3 - NBUF : i0 + 3;
        const int i4 = (i0 + 4 >= NBUF) ? i0 + 4 - NBUF : i0 + 4;
        ib = (i0 + 2 >= NBUF) ? i0 + 2 - NBUF : i0 + 2;

        stageStep(e + 3, i3);
        stageStep(e + 4, i4);
        loadFrags(i0, aA, bA);          // step e (landed)
        if (w) mfmaAll(aB, bB);         // step e-1 (carried frags)
        loadFrags(i1, aB, bB);          // step e+1 (landed)
        mfmaAll(aA, bA);                // step e

        asm volatile("s_waitcnt lgkmcnt(0)" ::: "memory");  // my ds_reads retired
        asm volatile("s_waitcnt vmcnt(4)" ::: "memory");    // e+2,e+3 landed
        __builtin_amdgcn_s_barrier();
        __builtin_amdgcn_sched_barrier(0);
    }
    mfmaAll(aB, bB);                    // step 127
    asm volatile("s_waitcnt vmcnt(0)" ::: "memory");        // drain clamped tails

    // ---- epilogue: C = acc + bias (C/D map: col=lane&15, row=quad*4+r) ----
    const int crow = quad * 4;
#pragma unroll
    for (int ni = 0; ni < 4; ++ni) {
        const int n  = n0 + wn + ni * 16 + l16;
        const float bv = bias[n];
#pragma unroll
        for (int mi = 0; mi < 8; ++mi) {
            const int mb = m0 + wm + mi * 16 + crow;
#pragma unroll
            for (int r = 0; r < 4; ++r)
                C[(size_t)(mb + r) * N + n] = acc[mi][ni][r] + bv;
        }
    }
}

// ---------------------------------------------------------------------------
extern "C" void kernel_launch(void* const* d_in, const int* in_sizes, int n_in,
                              void* d_out, int out_size, void* d_ws, size_t ws_size,
                              hipStream_t stream) {
    const float* x = (const float*)d_in[0];   // [B,S,K] fp32
    const float* W = (const float*)d_in[1];   // [N,K]   fp32
    const float* b = (const float*)d_in[2];   // [N]     fp32
    float* out = (float*)d_out;               // [B,S,N] fp32

    const int K = 4096;
    const int N = 4096;
    const int M = in_sizes[0] / K;            // 8192

    bf16_t* xb = (bf16_t*)d_ws;               // M*K bf16 = 64 MiB
    bf16_t* Wt = xb + (size_t)M * K;          // N*K bf16 = 32 MiB

    hipLaunchKernelGGL(fwht_rows_bf16, dim3(N), dim3(256), 0, stream, W, Wt);

    const int cvt_blocks = (int)(((size_t)M * K) / 8 / 256);  // 16384
    hipLaunchKernelGGL(cvt_f32_bf16, dim3(cvt_blocks), dim3(256), 0, stream,
                       (const float4*)x, (bf16x8*)xb);

    hipLaunchKernelGGL(gemm256_bt_bias, dim3(N / BN, M / BM), dim3(512), 0, stream,
                       xb, Wt, b, out, M, N, K);
}